// Round 7
// baseline (200.713 us; speedup 1.0000x reference)
//
#include <hip/hip_runtime.h>
#include <hip/hip_fp16.h>

#define DIMN 192
#define SD (DIMN * DIMN)             // 36864
#define CS (DIMN * DIMN * DIMN)      // 7077888
#define WIN_F 729.0f
#define NPART 768

typedef unsigned int uint32;

__device__ __forceinline__ float2 up32(uint32 u) {
    __half2 h = *(__half2*)&u;
    return __half22float2(h);
}
__device__ __forceinline__ uint32 pk32(float x, float y) {
    __half2 h = __floats2half2_rn(x, y);
    return *(uint32*)&h;
}

// ---------------------------------------------------------------------------
// K1: products + D-pass. Thread per (h,w) point, walks one 48-deep d-chunk
// (+8 halo). Raw (iv,jv) 9-ring in registers; running 5-channel window sums
// updated incrementally (departing products recomputed: 3 muls). Emits the
// D-box-summed {I, J, I2, J2, IJ} as f16. Reads I,J exactly once (+17% halo).
// grid = 4 chunks x 144 = 576 blocks x 256 threads.
// ---------------------------------------------------------------------------
__global__ __launch_bounds__(256) void k1_d(const float* __restrict__ I,
                                            const float* __restrict__ J,
                                            uint32* __restrict__ s01,
                                            uint32* __restrict__ s23,
                                            __half* __restrict__ s4) {
    const int chunk = blockIdx.x / 144;
    const int hw = (blockIdx.x % 144) * 256 + threadIdx.x;
    const int d0 = chunk * 48;

    float ri[9], rj[9];
#pragma unroll
    for (int k = 0; k < 9; k++) { ri[k] = 0.f; rj[k] = 0.f; }
    float r0 = 0.f, r1 = 0.f, r2 = 0.f, r3 = 0.f, r4 = 0.f;

    for (int i = 0; i < 56; i++) {
        const int ds = d0 - 4 + i;               // block-uniform predicate
        float iv = 0.f, jv = 0.f;
        if ((unsigned)ds < DIMN) {
            iv = I[ds * SD + hw];
            jv = J[ds * SD + hw];
        }
        const float oi = ri[0], oj = rj[0];      // slice leaving the window
        r0 += iv - oi;
        r1 += jv - oj;
        r2 += iv * iv - oi * oi;
        r3 += jv * jv - oj * oj;
        r4 += iv * jv - oi * oj;
#pragma unroll
        for (int k = 0; k < 8; k++) { ri[k] = ri[k + 1]; rj[k] = rj[k + 1]; }
        ri[8] = iv;
        rj[8] = jv;

        if (i >= 8) {
            const int o = (d0 + i - 8) * SD + hw;
            s01[o] = pk32(r0, r1);
            s23[o] = pk32(r2, r3);
            s4[o] = __float2half_rn(r4);
        }
    }
}

// ---------------------------------------------------------------------------
// K2: H-pass + W-pass + cc + partial reduce. One wave per (d, h-band, w-seg):
// lane l covers w = wseg*56 - 4 + l; outputs from lanes 4..59 (8-lane overlap
// between w-segments = the W zero-padding halo, since out-of-range lanes hold
// exact zeros). Walks 56 h-rows: H via raw-u32 9-ring; W via 8 __shfl taps.
// No LDS on the hot path, no per-row syncs -> loads pipeline freely.
// grid = 768 blocks x 256 (= 3072 waves: 192 d x 4 bands x 4 wsegs).
// ---------------------------------------------------------------------------
__global__ __launch_bounds__(256) void k2_hwcc(const uint32* __restrict__ s01,
                                               const uint32* __restrict__ s23,
                                               const __half* __restrict__ s4,
                                               double* __restrict__ partials) {
    const int tid = threadIdx.x;
    const int wg = blockIdx.x * 4 + (tid >> 6);  // 0..3071
    const int l = tid & 63;
    const int d = wg >> 4;
    const int band = (wg >> 2) & 3;
    const int wseg = wg & 3;
    const int w = wseg * 56 - 4 + l;
    const bool wok = (unsigned)w < DIMN;
    const int h0 = band * 48;
    const int cb = d * SD + w;                   // + hh*DIMN per row
    const bool outl = (l >= 4) && (l < 60) && wok;

    uint32 a01[9], a23[9];
    float a4[9];
#pragma unroll
    for (int k = 0; k < 9; k++) { a01[k] = 0u; a23[k] = 0u; a4[k] = 0.f; }
    float r0 = 0.f, r1 = 0.f, r2 = 0.f, r3 = 0.f, r4 = 0.f;
    double acc = 0.0;

    for (int i = 0; i < 56; i++) {
        const int hh = h0 - 4 + i;
        uint32 v01 = 0u, v23 = 0u;
        float v4 = 0.f;
        if (wok && (unsigned)hh < DIMN) {
            const int o = cb + hh * DIMN;
            v01 = s01[o];
            v23 = s23[o];
            v4 = __half2float(s4[o]);
        }
        const float2 n01 = up32(v01), n23 = up32(v23);
        const float2 o01 = up32(a01[0]), o23 = up32(a23[0]);
        r0 += n01.x - o01.x;
        r1 += n01.y - o01.y;
        r2 += n23.x - o23.x;
        r3 += n23.y - o23.y;
        r4 += v4 - a4[0];
#pragma unroll
        for (int k = 0; k < 8; k++) { a01[k] = a01[k + 1]; a23[k] = a23[k + 1]; a4[k] = a4[k + 1]; }
        a01[8] = v01;
        a23[8] = v23;
        a4[8] = v4;

        if (i >= 8) {
            // W-pass: 9-tap across lanes (taps of valid outputs never leave the wave)
            float S0 = r0, S1 = r1, S2 = r2, S3 = r3, S4 = r4;
#pragma unroll
            for (int k = 1; k <= 4; k++) {
                S0 += __shfl(r0, l - k, 64) + __shfl(r0, l + k, 64);
                S1 += __shfl(r1, l - k, 64) + __shfl(r1, l + k, 64);
                S2 += __shfl(r2, l - k, 64) + __shfl(r2, l + k, 64);
                S3 += __shfl(r3, l - k, 64) + __shfl(r3, l + k, 64);
                S4 += __shfl(r4, l - k, 64) + __shfl(r4, l + k, 64);
            }
            if (outl) {
                const float u_I = S0 / WIN_F;
                const float u_J = S1 / WIN_F;
                const float cross = S4 - u_J * S0 - u_I * S1 + u_I * u_J * WIN_F;
                const float I_var = S2 - 2.0f * u_I * S0 + u_I * u_I * WIN_F;
                const float J_var = S3 - 2.0f * u_J * S1 + u_J * u_J * WIN_F;
                acc += (double)(cross * cross / (I_var * J_var + 1e-5f));
            }
        }
    }

    __shared__ double wred[4];
#pragma unroll
    for (int off = 32; off > 0; off >>= 1) acc += __shfl_down(acc, off, 64);
    if ((tid & 63) == 0) wred[tid >> 6] = acc;
    __syncthreads();
    if (tid == 0) partials[blockIdx.x] = wred[0] + wred[1] + wred[2] + wred[3];
}

// ---------------------------------------------------------------------------
// K3: final reduce -> out[0] = -(mean cc)
// ---------------------------------------------------------------------------
__global__ void k_final(const double* __restrict__ partials, float* __restrict__ out) {
    __shared__ double wred[4];
    double acc = 0.0;
    for (int i = threadIdx.x; i < NPART; i += 256) acc += partials[i];
#pragma unroll
    for (int off = 32; off > 0; off >>= 1) acc += __shfl_down(acc, off, 64);
    if ((threadIdx.x & 63) == 0) wred[threadIdx.x >> 6] = acc;
    __syncthreads();
    if (threadIdx.x == 0) {
        const double total = wred[0] + wred[1] + wred[2] + wred[3];
        out[0] = -(float)(total / (double)CS);
    }
}

extern "C" void kernel_launch(void* const* d_in, const int* in_sizes, int n_in,
                              void* d_out, int out_size, void* d_ws, size_t ws_size,
                              hipStream_t stream) {
    const float* I = (const float*)d_in[0];   // y_true
    const float* J = (const float*)d_in[1];   // y_pred
    char* ws = (char*)d_ws;
    uint32* s01 = (uint32*)ws;                              // CS * 4 B
    uint32* s23 = (uint32*)(ws + (size_t)CS * 4);           // CS * 4 B
    __half* s4  = (__half*)(ws + (size_t)CS * 8);           // CS * 2 B
    double* partials = (double*)(ws + (size_t)CS * 10);     // NPART * 8 B
    float* out = (float*)d_out;

    hipLaunchKernelGGL(k1_d, dim3(576), dim3(256), 0, stream, I, J, s01, s23, s4);
    hipLaunchKernelGGL(k2_hwcc, dim3(768), dim3(256), 0, stream,
                       (const uint32*)s01, (const uint32*)s23, s4, partials);
    hipLaunchKernelGGL(k_final, dim3(1), dim3(256), 0, stream, partials, out);
}

// Round 8
// 156.970 us; speedup vs baseline: 1.2787x; 1.2787x over previous
//
#include <hip/hip_runtime.h>
#include <hip/hip_fp16.h>

#define DIMN 192
#define SD (DIMN * DIMN)             // 36864
#define CS (DIMN * DIMN * DIMN)      // 7077888
#define WIN_F 729.0f
#define NPART 768

typedef unsigned int uint32;

__device__ __forceinline__ float2 up32(uint32 u) {
    __half2 h = *(__half2*)&u;
    return __half22float2(h);
}
__device__ __forceinline__ uint32 pk32(float x, float y) {
    __half2 h = __floats2half2_rn(x, y);
    return *(uint32*)&h;
}

// ---------------------------------------------------------------------------
// K1: products + D-pass. Thread per (h,w), walks one 24-deep d-chunk (+8
// halo, 32 slices). Raw (iv,jv) 9-ring; 5 running window sums incremental.
// Stores interleaved: s0123[pt] = uint2{pk(s0,s1), pk(s2,s3)}, s4[pt] = half.
// grid = 8 chunks x 144 = 1152 blocks x 256 (18 waves/CU).
// ---------------------------------------------------------------------------
__global__ __launch_bounds__(256) void k1_d(const float* __restrict__ I,
                                            const float* __restrict__ J,
                                            uint2* __restrict__ s0123,
                                            __half* __restrict__ s4) {
    const int chunk = blockIdx.x / 144;
    const int hw = (blockIdx.x % 144) * 256 + threadIdx.x;
    const int d0 = chunk * 24;

    float ri[9], rj[9];
#pragma unroll
    for (int k = 0; k < 9; k++) { ri[k] = 0.f; rj[k] = 0.f; }
    float r0 = 0.f, r1 = 0.f, r2 = 0.f, r3 = 0.f, r4 = 0.f;

    for (int i = 0; i < 32; i++) {
        const int ds = d0 - 4 + i;               // block-uniform predicate
        float iv = 0.f, jv = 0.f;
        if ((unsigned)ds < DIMN) {
            iv = I[ds * SD + hw];
            jv = J[ds * SD + hw];
        }
        const float oi = ri[0], oj = rj[0];      // slice leaving the window
        r0 += iv - oi;
        r1 += jv - oj;
        r2 += iv * iv - oi * oi;
        r3 += jv * jv - oj * oj;
        r4 += iv * jv - oi * oj;
#pragma unroll
        for (int k = 0; k < 8; k++) { ri[k] = ri[k + 1]; rj[k] = rj[k + 1]; }
        ri[8] = iv;
        rj[8] = jv;

        if (i >= 8) {
            const int o = (d0 + i - 8) * SD + hw;
            s0123[o] = make_uint2(pk32(r0, r1), pk32(r2, r3));
            s4[o] = __float2half_rn(r4);
        }
    }
}

// ---------------------------------------------------------------------------
// K2: H-pass + W-pass + cc + partial reduce, pair-packed.
// Lane l owns the w-pair (we, we+1), we = w0 + 2l, w0 = -4 + wseg*72.
// Pairs are even-aligned so a pair is fully inside [0,192) or fully out.
// Walk 32 h-rows (24-output band + 8 halo): H-window = running sums with
// departing-row RE-READ (L2-resident; no register ring). W-pass: pack each
// channel's pair to half2, 4 shfl (l+-1, l+-2) -> 9-tap sums for BOTH outputs.
// Output ownership: we in [wseg*96, wseg*96+96) -> each w counted once.
// grid = 768 blocks x 256 = 3072 waves (192 d x 8 bands x 2 wsegs).
// ---------------------------------------------------------------------------
__global__ __launch_bounds__(256) void k2_hwcc(const uint2* __restrict__ s0123,
                                               const __half* __restrict__ s4,
                                               double* __restrict__ partials) {
    const int tid = threadIdx.x;
    const int l = tid & 63;
    const int wg = blockIdx.x * 4 + (tid >> 6);    // 0..3071
    const int wseg = wg & 1;
    const int band = (wg >> 1) & 7;
    const int d = wg >> 4;                          // 0..191
    const int h0 = band * 24;
    const int w0 = -4 + wseg * 72;
    const int we = w0 + 2 * l;
    const bool pok = ((unsigned)we < DIMN);         // pair fully in-volume
    const int lo = wseg * 96;
    const bool f = pok && (we >= lo) && (we < lo + 96);  // pair ownership
    const int cb = d * SD + we;

    float re0 = 0.f, re1 = 0.f, re2 = 0.f, re3 = 0.f, re4 = 0.f;
    float ro0 = 0.f, ro1 = 0.f, ro2 = 0.f, ro3 = 0.f, ro4 = 0.f;
    double acc = 0.0;

    for (int i = 0; i < 32; ++i) {
        const int hh = h0 - 4 + i;
        uint4 qa = make_uint4(0u, 0u, 0u, 0u);
        uint32 qa4 = 0u;
        if (pok && (unsigned)hh < DIMN) {
            const int o = cb + hh * DIMN;
            qa = *(const uint4*)(s0123 + o);
            qa4 = *(const uint32*)(s4 + o);
        }
        uint4 qs = make_uint4(0u, 0u, 0u, 0u);
        uint32 qs4 = 0u;
        const int hd = hh - 9;                      // row leaving the window
        if (i >= 9 && pok && (unsigned)hd < DIMN) {
            const int o = cb + hd * DIMN;
            qs = *(const uint4*)(s0123 + o);
            qs4 = *(const uint32*)(s4 + o);
        }
        float2 t;
        t = up32(qa.x); re0 += t.x; re1 += t.y;
        t = up32(qs.x); re0 -= t.x; re1 -= t.y;
        t = up32(qa.y); re2 += t.x; re3 += t.y;
        t = up32(qs.y); re2 -= t.x; re3 -= t.y;
        t = up32(qa.z); ro0 += t.x; ro1 += t.y;
        t = up32(qs.z); ro0 -= t.x; ro1 -= t.y;
        t = up32(qa.w); ro2 += t.x; ro3 += t.y;
        t = up32(qs.w); ro2 -= t.x; ro3 -= t.y;
        t = up32(qa4);  re4 += t.x; ro4 += t.y;
        t = up32(qs4);  re4 -= t.x; ro4 -= t.y;

        if (i >= 8) {
            float Se[5], So[5];
#define WTAP(c, rE, rO)                                                       \
            {                                                                 \
                const uint32 tc = pk32(rE, rO);                               \
                const float2 m2 = up32((uint32)__shfl((int)tc, l - 2, 64));   \
                const float2 m1 = up32((uint32)__shfl((int)tc, l - 1, 64));   \
                const float2 p1 = up32((uint32)__shfl((int)tc, l + 1, 64));   \
                const float2 p2 = up32((uint32)__shfl((int)tc, l + 2, 64));   \
                const float M = m1.x + m1.y + rE + rO + p1.x + p1.y;          \
                Se[c] = M + m2.x + m2.y + p2.x;                               \
                So[c] = M + m2.y + p2.x + p2.y;                               \
            }
            WTAP(0, re0, ro0)
            WTAP(1, re1, ro1)
            WTAP(2, re2, ro2)
            WTAP(3, re3, ro3)
            WTAP(4, re4, ro4)
#undef WTAP
            if (f) {
                {
                    const float u_I = Se[0] / WIN_F;
                    const float u_J = Se[1] / WIN_F;
                    const float cross = Se[4] - u_J * Se[0] - u_I * Se[1] + u_I * u_J * WIN_F;
                    const float I_var = Se[2] - 2.0f * u_I * Se[0] + u_I * u_I * WIN_F;
                    const float J_var = Se[3] - 2.0f * u_J * Se[1] + u_J * u_J * WIN_F;
                    acc += (double)(cross * cross / (I_var * J_var + 1e-5f));
                }
                {
                    const float u_I = So[0] / WIN_F;
                    const float u_J = So[1] / WIN_F;
                    const float cross = So[4] - u_J * So[0] - u_I * So[1] + u_I * u_J * WIN_F;
                    const float I_var = So[2] - 2.0f * u_I * So[0] + u_I * u_I * WIN_F;
                    const float J_var = So[3] - 2.0f * u_J * So[1] + u_J * u_J * WIN_F;
                    acc += (double)(cross * cross / (I_var * J_var + 1e-5f));
                }
            }
        }
    }

    __shared__ double wred[4];
#pragma unroll
    for (int off = 32; off > 0; off >>= 1) acc += __shfl_down(acc, off, 64);
    if ((tid & 63) == 0) wred[tid >> 6] = acc;
    __syncthreads();
    if (tid == 0) partials[blockIdx.x] = wred[0] + wred[1] + wred[2] + wred[3];
}

// ---------------------------------------------------------------------------
// K3: final reduce -> out[0] = -(mean cc)
// ---------------------------------------------------------------------------
__global__ void k_final(const double* __restrict__ partials, float* __restrict__ out) {
    __shared__ double wred[4];
    double acc = 0.0;
    for (int i = threadIdx.x; i < NPART; i += 256) acc += partials[i];
#pragma unroll
    for (int off = 32; off > 0; off >>= 1) acc += __shfl_down(acc, off, 64);
    if ((threadIdx.x & 63) == 0) wred[threadIdx.x >> 6] = acc;
    __syncthreads();
    if (threadIdx.x == 0) {
        const double total = wred[0] + wred[1] + wred[2] + wred[3];
        out[0] = -(float)(total / (double)CS);
    }
}

extern "C" void kernel_launch(void* const* d_in, const int* in_sizes, int n_in,
                              void* d_out, int out_size, void* d_ws, size_t ws_size,
                              hipStream_t stream) {
    const float* I = (const float*)d_in[0];   // y_true
    const float* J = (const float*)d_in[1];   // y_pred
    char* ws = (char*)d_ws;
    uint2*  s0123 = (uint2*)ws;                             // CS * 8 B
    __half* s4    = (__half*)(ws + (size_t)CS * 8);         // CS * 2 B
    double* partials = (double*)(ws + (size_t)CS * 10);     // NPART * 8 B
    float* out = (float*)d_out;

    hipLaunchKernelGGL(k1_d, dim3(1152), dim3(256), 0, stream, I, J, s0123, s4);
    hipLaunchKernelGGL(k2_hwcc, dim3(768), dim3(256), 0, stream,
                       (const uint2*)s0123, (const __half*)s4, partials);
    hipLaunchKernelGGL(k_final, dim3(1), dim3(256), 0, stream, partials, out);
}